// Round 19
// baseline (98.155 us; speedup 1.0000x reference)
//
#include <hip/hip_runtime.h>

#define BN 4
#define LN 1024
#define SN 1024
#define HN 8
#define EN 64
#define OFF_ATT (BN * LN * HN * EN)
#define OFF_ENT (OFF_ATT + BN * HN * LN * SN)

// workspace byte offsets (need ~25 MB)
#define WS_MW 0u                          // f16 mask (pre-scaled by 0.125*log2e), 16 MB
#define WS_KB 16777216u                   // bf16 K, 4 MB
#define WS_VT (WS_KB + 4194304u)          // bf16 V^T, 4 MB

// att/mask LDS tile: 32 rows, pitch 2064 B (516 dwords == 4 mod 32 banks)
#define APITCH 2064

#define LOG2E 1.44269504f
#define LN2 0.69314718f
#define SCL (0.125f * LOG2E)

typedef __attribute__((ext_vector_type(8))) __bf16 bf16x8;
typedef __attribute__((ext_vector_type(4))) float f32x4;
typedef __attribute__((ext_vector_type(4))) unsigned int uint4v;
typedef __attribute__((ext_vector_type(2))) unsigned int uint2v;
typedef __attribute__((ext_vector_type(4))) _Float16 f16x4;

// blockIdx.x (0..127) encodes (lbHi, b, lbLo): batch-siblings of an
// (h,l-tile) are 8 blocks apart -> same XCD -> mw slices L2-hot.
__device__ __forceinline__ void decode_block(int x, int& b, int& lb) {
  int lbLo = x & 7;
  b = (x >> 3) & 3;
  lb = (x >> 5) * 8 + lbLo;  // 0..31 (32-row tiles)
}

// round-to-nearest-even fp32 -> bf16 pair, packed (lo in low half)
__device__ __forceinline__ unsigned int rne2(float x, float y) {
  unsigned int ux = __float_as_uint(x), uy = __float_as_uint(y);
  ux += 0x7fffu + ((ux >> 16) & 1u);
  uy += 0x7fffu + ((uy >> 16) & 1u);
  return (ux >> 16) | (uy & 0xffff0000u);
}

__device__ __forceinline__ uint4v pack8_rne(float4 a, float4 b) {
  return uint4v{rne2(a.x, a.y), rne2(a.z, a.w), rne2(b.x, b.y), rne2(b.z, b.w)};
}

// ---------------- fused prep kernel (mask + K + V^T) ----------------
__global__ __launch_bounds__(256) void k_prep(
    const float* __restrict__ kk, const float* __restrict__ vv,
    const float* __restrict__ phi, const float* __restrict__ u,
    const float* __restrict__ p_logtau, const float* __restrict__ p_thresh,
    _Float16* __restrict__ mw, unsigned short* __restrict__ kb,
    unsigned short* __restrict__ vT) {
  const int bx = blockIdx.x;
  if (bx < 8192) {
    const float tau = fminf(fmaxf(__expf(p_logtau[0]), 0.1f), 5.0f);
    const float rtau = 1.0f / tau;
    const float thr = fminf(fmaxf(p_thresh[0], 0.01f), 0.99f);
    int idx = (bx * 256 + threadIdx.x) * 4;
    float4 u4 = *(const float4*)(u + idx);
    float4 p4 = *(const float4*)(phi + idx);
    float uu[4] = {u4.x, u4.y, u4.z, u4.w};
    float pp[4] = {p4.x, p4.y, p4.z, p4.w};
    f16x4 o;
#pragma unroll
    for (int i = 0; i < 4; ++i) {
      float g = __logf(__fdividef(uu[i] + 1e-8f, 1.0f - uu[i] + 1e-8f));
      float z = (g + pp[i]) * rtau;
      float sig = __fdividef(1.0f, 1.0f + __expf(-z));
      // pre-scaled into base-2 units: pm2 = pm * 0.125 * log2(e)
      o[i] = (_Float16)(-10000.0f * fmaxf(thr - sig, 0.0f) * SCL);
    }
    *(f16x4*)(mw + idx) = o;
  } else if (bx < 9216) {
    int gid = (bx - 8192) * 256 + threadIdx.x;
    int e8 = gid & 7;
    int tmp = gid >> 3;
    int h = tmp & 7;
    int bs = tmp >> 3;
    int s = bs & 1023;
    int b = bs >> 10;
    const float* src = kk + (size_t)gid * 8;
    float4 a = *(const float4*)src;
    float4 bq = *(const float4*)(src + 4);
    *(uint4v*)(kb + (((size_t)(b * 8 + h) * 1024 + s) * 64) + e8 * 8) =
        pack8_rne(a, bq);
  } else {
    int gid = (bx - 9216) * 256 + threadIdx.x;
    int s8 = gid & 127;
    int t1 = gid >> 7;
    int e = t1 & 63;
    int t2 = t1 >> 6;
    int h = t2 & 7;
    int b = t2 >> 3;
    float x[8];
#pragma unroll
    for (int j = 0; j < 8; ++j)
      x[j] = vv[((size_t)(b * 1024 + s8 * 8 + j) * 8 + h) * 64 + e];
    uint4v pv = pack8_rne(float4{x[0], x[1], x[2], x[3]},
                          float4{x[4], x[5], x[6], x[7]});
    *(uint4v*)(vT + ((size_t)(b * 8 + h) * 64 + e) * 1024 + s8 * 8) = pv;
  }
}

// ---------------- fused: 32 q-rows/block, merged q-tile QK ----------------
// 8 waves (512 thr). Wave w owns s-range [w*128, w*128+128). K fragments
// loaded ONCE for both 16-row q-tiles (accs[16] = 64 AGPR). Base-2 softmax.
// Epilogue order after bar4: PV FIRST (dependent LDS+MFMA chains start
// immediately; vT batch-0 prefetched), att NT store burst SECOND (drains
// during V-partial reduce + kernel tail instead of ahead of PV).
__global__ __launch_bounds__(512, 4) void k_fused(
    const float* __restrict__ q, const unsigned short* __restrict__ kb,
    const unsigned short* __restrict__ vT, const _Float16* __restrict__ mw,
    const int* __restrict__ p_causal, float* __restrict__ out) {
  int b, lb;
  decode_block(blockIdx.x, b, lb);
  const int h = blockIdx.y;
  const int tid = threadIdx.x;
  const int w = __builtin_amdgcn_readfirstlane(tid >> 6);  // 0..7
  const int c = tid & 63;
  const int cl = c & 15;
  const int cg = c >> 4;

  __shared__ __align__(16) unsigned char lds_att[32 * APITCH];  // 66 KB
  __shared__ float red0[2][8][16], redZ[2][8][16], redE[2][8][16];

  const int causal = p_causal[0];
  const unsigned short* kbb = kb + ((size_t)(b * 8 + h) * 1024) * 64;

  // ---- phase 0: stage 32 mask rows (64 KB) coalesced into LDS
  {
    const unsigned char* gmask =
        (const unsigned char*)(mw + ((size_t)h * LN + lb * 32) * SN);
    uint4v mk[8];
#pragma unroll
    for (int i = 0; i < 8; ++i)
      mk[i] = *(const uint4v*)(gmask + i * 8192 + tid * 16);
#pragma unroll
    for (int i = 0; i < 8; ++i) {
      int goff = i * 8192 + tid * 16;
      *(uint4v*)(lds_att + (goff >> 11) * APITCH + (goff & 2047)) = mk[i];
    }
  }

  // ---- Q fragments, single bf16 (RNE), both q-tiles
  uint4v qf[2][2];
#pragma unroll
  for (int qt = 0; qt < 2; ++qt)
#pragma unroll
    for (int cc = 0; cc < 2; ++cc) {
      const float* qp = q + (((size_t)b * LN + lb * 32 + qt * 16 + cl) * HN + h) * EN +
                        cc * 32 + cg * 8;
      float4 a = *(const float4*)qp;
      float4 bq = *(const float4*)(qp + 4);
      qf[qt][cc] = pack8_rne(a, bq);
    }

  __syncthreads();  // bar1: mask staged

  // ---- QK^T: K loaded ONCE per tile, MFMA'd against both q-tiles
  f32x4 accs[16];  // [qt*8 + tg]
#pragma unroll
  for (int tgb = 0; tgb < 2; ++tgb) {
    uint4v kf[4][2];
#pragma unroll
    for (int t2 = 0; t2 < 4; ++t2)
#pragma unroll
      for (int cc = 0; cc < 2; ++cc)
        kf[t2][cc] = *(const uint4v*)(kbb +
                                      (size_t)(w * 128 + (tgb * 4 + t2) * 16 + cl) * 64 +
                                      cc * 32 + cg * 8);
#pragma unroll
    for (int t2 = 0; t2 < 4; ++t2)
#pragma unroll
      for (int qt = 0; qt < 2; ++qt) {
        f32x4 acc = f32x4{0.f, 0.f, 0.f, 0.f};
#pragma unroll
        for (int cc = 0; cc < 2; ++cc)
          acc = __builtin_amdgcn_mfma_f32_16x16x32_bf16(
              __builtin_bit_cast(bf16x8, kf[t2][cc]),
              __builtin_bit_cast(bf16x8, qf[qt][cc]), acc, 0, 0, 0);
        accs[qt * 8 + tgb * 4 + t2] = acc;
      }
  }

  // ---- mask (LDS f16, base-2 units) + integer causal + max, both q-tiles
  float mx[2] = {-3.0e38f, -3.0e38f};
#pragma unroll
  for (int qt = 0; qt < 2; ++qt) {
    const int l = lb * 32 + qt * 16 + cl;
    const unsigned char* mrow = lds_att + (qt * 16 + cl) * APITCH;
#pragma unroll
    for (int tg = 0; tg < 8; ++tg) {
      const int s0 = w * 128 + tg * 16 + cg * 4;
      f16x4 m4 = *(const f16x4*)(mrow + s0 * 2);
#pragma unroll
      for (int r = 0; r < 4; ++r) {
        float v = fmaf(accs[qt * 8 + tg][r], SCL, (float)m4[r]);
        bool maskd = (causal != 0) && (s0 + r > l);
        v = maskd ? -1.0e30f : v;
        accs[qt * 8 + tg][r] = v;
        mx[qt] = fmaxf(mx[qt], v);
      }
    }
    mx[qt] = fmaxf(mx[qt], __shfl_xor(mx[qt], 16, 64));
    mx[qt] = fmaxf(mx[qt], __shfl_xor(mx[qt], 32, 64));
    if (cg == 0) red0[qt][w][cl] = mx[qt];
  }
  __syncthreads();  // bar2 (both q-tile maxes)

#pragma unroll
  for (int qt = 0; qt < 2; ++qt) {
    float bmx = red0[qt][0][cl];
#pragma unroll
    for (int i = 1; i < 8; ++i) bmx = fmaxf(bmx, red0[qt][i][cl]);
    float z = 0.f, e = 0.f;
#pragma unroll
    for (int tg = 0; tg < 8; ++tg) {
#pragma unroll
      for (int r = 0; r < 4; ++r) {
        float tt = accs[qt * 8 + tg][r] - bmx;
        float ex = exp2f(tt);  // native v_exp_f32 (base-2)
        z += ex;
        e = fmaf(ex, tt, e);   // ex==0 when masked: 0*finite, no NaN
        accs[qt * 8 + tg][r] = ex;
      }
    }
    z += __shfl_xor(z, 16, 64);
    z += __shfl_xor(z, 32, 64);
    e += __shfl_xor(e, 16, 64);
    e += __shfl_xor(e, 32, 64);
    if (cg == 0) { redZ[qt][w][cl] = z; redE[qt][w][cl] = e; }
  }
  __syncthreads();  // bar3 (both q-tile sums)

#pragma unroll
  for (int qt = 0; qt < 2; ++qt) {
    const int l = lb * 32 + qt * 16 + cl;
    float Z = redZ[qt][0][cl], E = redE[qt][0][cl];
#pragma unroll
    for (int i = 1; i < 8; ++i) { Z += redZ[qt][i][cl]; E += redE[qt][i][cl]; }
    const float rz = __fdividef(1.0f, Z);
    if (w == 0 && cg == 0)
      out[OFF_ENT + ((size_t)b * HN + h) * LN + l] = LN2 * (__log2f(Z) - E * rz);

    // normalized bf16 att into LDS (own row, own s-range — no hazard)
    unsigned char* arow = lds_att + (qt * 16 + cl) * APITCH;
#pragma unroll
    for (int tg = 0; tg < 8; ++tg) {
      const int s0 = w * 128 + tg * 16 + cg * 4;
      float ax = accs[qt * 8 + tg][0] * rz, ay = accs[qt * 8 + tg][1] * rz;
      float az = accs[qt * 8 + tg][2] * rz, aw = accs[qt * 8 + tg][3] * rz;
      uint2v pk = uint2v{rne2(ax, ay), rne2(az, aw)};
      *(uint2v*)(arow + s0 * 2) = pk;
    }
  }

  // ---- vT batch-0 prefetch (independent of LDS)
  const int et = w & 3, sh = w >> 2;
  const unsigned short* vbb =
      vT + ((size_t)(b * 8 + h) * 64 + et * 16 + cl) * 1024 + sh * 512;
  uint4v vf0[8];
#pragma unroll
  for (int j = 0; j < 8; ++j)
    vf0[j] = *(const uint4v*)(vbb + j * 32 + cg * 8);

  __syncthreads();  // bar4: full 32-row att tile visible

  // ---- PV FIRST: wave w -> (e-tile et, s-half sh); vT fragments reused
  // across both q-tiles. 32 MFMAs/wave. (att store burst moved after PV.)
  f32x4 acc00 = f32x4{0.f, 0.f, 0.f, 0.f}, acc01 = f32x4{0.f, 0.f, 0.f, 0.f};
  f32x4 acc10 = f32x4{0.f, 0.f, 0.f, 0.f}, acc11 = f32x4{0.f, 0.f, 0.f, 0.f};
#pragma unroll
  for (int scb = 0; scb < 2; ++scb) {
    uint4v vf[8];
    if (scb == 0) {
#pragma unroll
      for (int j = 0; j < 8; ++j) vf[j] = vf0[j];
    } else {
#pragma unroll
      for (int j = 0; j < 8; ++j)
        vf[j] = *(const uint4v*)(vbb + 256 + j * 32 + cg * 8);
    }
#pragma unroll
    for (int qt = 0; qt < 2; ++qt) {
      uint4v af[8];
#pragma unroll
      for (int j = 0; j < 8; ++j)
        af[j] = *(const uint4v*)(lds_att + (qt * 16 + cl) * APITCH +
                                 (sh * 512 + scb * 256 + j * 32 + cg * 8) * 2);
#pragma unroll
      for (int j = 0; j < 8; ++j) {
        bf16x8 a8 = __builtin_bit_cast(bf16x8, vf[j]);
        bf16x8 b8 = __builtin_bit_cast(bf16x8, af[j]);
        if (qt == 0) {
          if (j & 1)
            acc01 = __builtin_amdgcn_mfma_f32_16x16x32_bf16(a8, b8, acc01, 0, 0, 0);
          else
            acc00 = __builtin_amdgcn_mfma_f32_16x16x32_bf16(a8, b8, acc00, 0, 0, 0);
        } else {
          if (j & 1)
            acc11 = __builtin_amdgcn_mfma_f32_16x16x32_bf16(a8, b8, acc11, 0, 0, 0);
          else
            acc10 = __builtin_amdgcn_mfma_f32_16x16x32_bf16(a8, b8, acc10, 0, 0, 0);
        }
      }
    }
  }
  f32x4 sum0 = acc00 + acc01;
  f32x4 sum1 = acc10 + acc11;

  // ---- att NT store burst SECOND: wave w -> rows w*4..w*4+3
  {
    float* abase = out + OFF_ATT + (((size_t)b * HN + h) * LN + lb * 32) * SN;
#pragma unroll
    for (int rr = 0; rr < 4; ++rr) {
      const int row = w * 4 + rr;
      const unsigned char* src = lds_att + row * APITCH;
      float* dst = abase + (size_t)row * SN;
#pragma unroll
      for (int it = 0; it < 4; ++it) {
        uint2v pk = *(const uint2v*)(src + it * 512 + c * 8);
        f32x4 o = f32x4{__uint_as_float(pk.x << 16),
                        __uint_as_float(pk.x & 0xffff0000u),
                        __uint_as_float(pk.y << 16),
                        __uint_as_float(pk.y & 0xffff0000u)};
        __builtin_nontemporal_store(o, (f32x4*)(dst + it * 256 + c * 4));
      }
    }
  }

  __syncthreads();  // bar5: all PV att reads + att-write LDS reads done

  *(f32x4*)(lds_att + cl * APITCH + sh * 1024 + (et * 16 + cg * 4) * 4) = sum0;
  *(f32x4*)(lds_att + (16 + cl) * APITCH + sh * 1024 + (et * 16 + cg * 4) * 4) = sum1;

  __syncthreads();  // bar6: partials ready

  // ---- V: 2-way s-half reduce + coalesced NT store (512 thr = 32 r x 16 e4)
  {
    const int r = tid >> 4, e4 = tid & 15;
    f32x4 p0 = *(const f32x4*)(lds_att + r * APITCH + e4 * 16);
    f32x4 p1 = *(const f32x4*)(lds_att + r * APITCH + 1024 + e4 * 16);
    f32x4 s = p0 + p1;
    float* dst = out + (((size_t)b * LN + lb * 32 + r) * HN + h) * EN + e4 * 4;
    __builtin_nontemporal_store(s, (f32x4*)dst);
  }
}

extern "C" void kernel_launch(void* const* d_in, const int* in_sizes, int n_in,
                              void* d_out, int out_size, void* d_ws, size_t ws_size,
                              hipStream_t stream) {
  (void)in_sizes; (void)n_in; (void)out_size; (void)ws_size;
  const float* q   = (const float*)d_in[0];
  const float* k   = (const float*)d_in[1];
  const float* v   = (const float*)d_in[2];
  const float* phi = (const float*)d_in[4];
  const float* u   = (const float*)d_in[5];
  const float* lt  = (const float*)d_in[6];
  const float* th  = (const float*)d_in[7];
  const int*   cm  = (const int*)d_in[8];
  float* out = (float*)d_out;

  _Float16* mw = (_Float16*)((char*)d_ws + WS_MW);
  unsigned short* kb = (unsigned short*)((char*)d_ws + WS_KB);
  unsigned short* vT = (unsigned short*)((char*)d_ws + WS_VT);

  k_prep<<<dim3(10240), dim3(256), 0, stream>>>(k, v, phi, u, lt, th, mw, kb, vT);
  k_fused<<<dim3(128, 8, 1), dim3(512), 0, stream>>>(q, kb, vT, mw, cm, out);
}

// Round 20
// 93.005 us; speedup vs baseline: 1.0554x; 1.0554x over previous
//
#include <hip/hip_runtime.h>

#define BN 4
#define LN 1024
#define SN 1024
#define HN 8
#define EN 64
#define OFF_ATT (BN * LN * HN * EN)
#define OFF_ENT (OFF_ATT + BN * HN * LN * SN)

// workspace byte offsets (need ~25 MB)
#define WS_MW 0u                          // f16 mask (pre-scaled by 0.125*log2e), 16 MB
#define WS_KB 16777216u                   // bf16 K, 4 MB
#define WS_VT (WS_KB + 4194304u)          // bf16 V^T, 4 MB

// att/mask LDS tile: 32 rows, pitch 2064 B (516 dwords == 4 mod 32 banks)
#define APITCH 2064

#define LOG2E 1.44269504f
#define LN2 0.69314718f
#define SCL (0.125f * LOG2E)

typedef __attribute__((ext_vector_type(8))) __bf16 bf16x8;
typedef __attribute__((ext_vector_type(4))) float f32x4;
typedef __attribute__((ext_vector_type(4))) unsigned int uint4v;
typedef __attribute__((ext_vector_type(2))) unsigned int uint2v;
typedef __attribute__((ext_vector_type(4))) _Float16 f16x4;

// blockIdx.x (0..127) encodes (lbHi, b, lbLo): batch-siblings of an
// (h,l-tile) are 8 blocks apart -> same XCD -> mw slices L2-hot.
__device__ __forceinline__ void decode_block(int x, int& b, int& lb) {
  int lbLo = x & 7;
  b = (x >> 3) & 3;
  lb = (x >> 5) * 8 + lbLo;  // 0..31 (32-row tiles)
}

// round-to-nearest-even fp32 -> bf16 pair, packed (lo in low half)
__device__ __forceinline__ unsigned int rne2(float x, float y) {
  unsigned int ux = __float_as_uint(x), uy = __float_as_uint(y);
  ux += 0x7fffu + ((ux >> 16) & 1u);
  uy += 0x7fffu + ((uy >> 16) & 1u);
  return (ux >> 16) | (uy & 0xffff0000u);
}

__device__ __forceinline__ uint4v pack8_rne(float4 a, float4 b) {
  return uint4v{rne2(a.x, a.y), rne2(a.z, a.w), rne2(b.x, b.y), rne2(b.z, b.w)};
}

// ---------------- fused prep kernel (mask + K + V^T) ----------------
__global__ __launch_bounds__(256) void k_prep(
    const float* __restrict__ kk, const float* __restrict__ vv,
    const float* __restrict__ phi, const float* __restrict__ u,
    const float* __restrict__ p_logtau, const float* __restrict__ p_thresh,
    _Float16* __restrict__ mw, unsigned short* __restrict__ kb,
    unsigned short* __restrict__ vT) {
  const int bx = blockIdx.x;
  if (bx < 8192) {
    const float tau = fminf(fmaxf(__expf(p_logtau[0]), 0.1f), 5.0f);
    const float rtau = 1.0f / tau;
    const float thr = fminf(fmaxf(p_thresh[0], 0.01f), 0.99f);
    int idx = (bx * 256 + threadIdx.x) * 4;
    float4 u4 = *(const float4*)(u + idx);
    float4 p4 = *(const float4*)(phi + idx);
    float uu[4] = {u4.x, u4.y, u4.z, u4.w};
    float pp[4] = {p4.x, p4.y, p4.z, p4.w};
    f16x4 o;
#pragma unroll
    for (int i = 0; i < 4; ++i) {
      float g = __logf(__fdividef(uu[i] + 1e-8f, 1.0f - uu[i] + 1e-8f));
      float z = (g + pp[i]) * rtau;
      float sig = __fdividef(1.0f, 1.0f + __expf(-z));
      // pre-scaled into base-2 units: pm2 = pm * 0.125 * log2(e)
      o[i] = (_Float16)(-10000.0f * fmaxf(thr - sig, 0.0f) * SCL);
    }
    *(f16x4*)(mw + idx) = o;
  } else if (bx < 9216) {
    int gid = (bx - 8192) * 256 + threadIdx.x;
    int e8 = gid & 7;
    int tmp = gid >> 3;
    int h = tmp & 7;
    int bs = tmp >> 3;
    int s = bs & 1023;
    int b = bs >> 10;
    const float* src = kk + (size_t)gid * 8;
    float4 a = *(const float4*)src;
    float4 bq = *(const float4*)(src + 4);
    *(uint4v*)(kb + (((size_t)(b * 8 + h) * 1024 + s) * 64) + e8 * 8) =
        pack8_rne(a, bq);
  } else {
    int gid = (bx - 9216) * 256 + threadIdx.x;
    int s8 = gid & 127;
    int t1 = gid >> 7;
    int e = t1 & 63;
    int t2 = t1 >> 6;
    int h = t2 & 7;
    int b = t2 >> 3;
    float x[8];
#pragma unroll
    for (int j = 0; j < 8; ++j)
      x[j] = vv[((size_t)(b * 1024 + s8 * 8 + j) * 8 + h) * 64 + e];
    uint4v pv = pack8_rne(float4{x[0], x[1], x[2], x[3]},
                          float4{x[4], x[5], x[6], x[7]});
    *(uint4v*)(vT + ((size_t)(b * 8 + h) * 64 + e) * 1024 + s8 * 8) = pv;
  }
}

// ---------------- fused: 32 q-rows/block, merged q-tile QK ----------------
// 8 waves (512 thr). Wave w owns s-range [w*128, w*128+128). K fragments
// loaded ONCE for both 16-row q-tiles (accs[16] = 64 AGPR). Base-2 softmax.
// R20: (a) staging barrier moved AFTER the QK MFMAs (QK touches only
// global+regs, so mask LDS-writes drain under QK's load latency);
// (b) single-barrier online-softmax merge: per-wave (m,z,e) triples, one
// barrier, per-thread merge with 2^(mi-M) scaling — barriers 6 -> 5.
__global__ __launch_bounds__(512, 4) void k_fused(
    const float* __restrict__ q, const unsigned short* __restrict__ kb,
    const unsigned short* __restrict__ vT, const _Float16* __restrict__ mw,
    const int* __restrict__ p_causal, float* __restrict__ out) {
  int b, lb;
  decode_block(blockIdx.x, b, lb);
  const int h = blockIdx.y;
  const int tid = threadIdx.x;
  const int w = __builtin_amdgcn_readfirstlane(tid >> 6);  // 0..7
  const int c = tid & 63;
  const int cl = c & 15;
  const int cg = c >> 4;

  __shared__ __align__(16) unsigned char lds_att[32 * APITCH];  // 66 KB
  __shared__ float redM[2][8][16], redZ[2][8][16], redE[2][8][16];

  const int causal = p_causal[0];
  const unsigned short* kbb = kb + ((size_t)(b * 8 + h) * 1024) * 64;

  // ---- phase 0: stage 32 mask rows (64 KB) coalesced into LDS
  {
    const unsigned char* gmask =
        (const unsigned char*)(mw + ((size_t)h * LN + lb * 32) * SN);
    uint4v mk[8];
#pragma unroll
    for (int i = 0; i < 8; ++i)
      mk[i] = *(const uint4v*)(gmask + i * 8192 + tid * 16);
#pragma unroll
    for (int i = 0; i < 8; ++i) {
      int goff = i * 8192 + tid * 16;
      *(uint4v*)(lds_att + (goff >> 11) * APITCH + (goff & 2047)) = mk[i];
    }
  }

  // ---- Q fragments, single bf16 (RNE), both q-tiles
  uint4v qf[2][2];
#pragma unroll
  for (int qt = 0; qt < 2; ++qt)
#pragma unroll
    for (int cc = 0; cc < 2; ++cc) {
      const float* qp = q + (((size_t)b * LN + lb * 32 + qt * 16 + cl) * HN + h) * EN +
                        cc * 32 + cg * 8;
      float4 a = *(const float4*)qp;
      float4 bq = *(const float4*)(qp + 4);
      qf[qt][cc] = pack8_rne(a, bq);
    }

  // ---- QK^T: K loaded ONCE per tile, MFMA'd against both q-tiles.
  // (No barrier yet: QK is global+reg only; staging writes drain underneath.)
  f32x4 accs[16];  // [qt*8 + tg]
#pragma unroll
  for (int tgb = 0; tgb < 2; ++tgb) {
    uint4v kf[4][2];
#pragma unroll
    for (int t2 = 0; t2 < 4; ++t2)
#pragma unroll
      for (int cc = 0; cc < 2; ++cc)
        kf[t2][cc] = *(const uint4v*)(kbb +
                                      (size_t)(w * 128 + (tgb * 4 + t2) * 16 + cl) * 64 +
                                      cc * 32 + cg * 8);
#pragma unroll
    for (int t2 = 0; t2 < 4; ++t2)
#pragma unroll
      for (int qt = 0; qt < 2; ++qt) {
        f32x4 acc = f32x4{0.f, 0.f, 0.f, 0.f};
#pragma unroll
        for (int cc = 0; cc < 2; ++cc)
          acc = __builtin_amdgcn_mfma_f32_16x16x32_bf16(
              __builtin_bit_cast(bf16x8, kf[t2][cc]),
              __builtin_bit_cast(bf16x8, qf[qt][cc]), acc, 0, 0, 0);
        accs[qt * 8 + tgb * 4 + t2] = acc;
      }
  }

  __syncthreads();  // bar1: mask staged (moved below QK)

  // ---- mask (LDS f16, base-2 units) + integer causal + per-wave max,
  // then per-wave z/e vs OWN max (online-softmax local pass)
  float mx[2];
#pragma unroll
  for (int qt = 0; qt < 2; ++qt) {
    const int l = lb * 32 + qt * 16 + cl;
    const unsigned char* mrow = lds_att + (qt * 16 + cl) * APITCH;
    float m = -3.0e38f;
#pragma unroll
    for (int tg = 0; tg < 8; ++tg) {
      const int s0 = w * 128 + tg * 16 + cg * 4;
      f16x4 m4 = *(const f16x4*)(mrow + s0 * 2);
#pragma unroll
      for (int r = 0; r < 4; ++r) {
        float v = fmaf(accs[qt * 8 + tg][r], SCL, (float)m4[r]);
        bool maskd = (causal != 0) && (s0 + r > l);
        v = maskd ? -1.0e30f : v;
        accs[qt * 8 + tg][r] = v;
        m = fmaxf(m, v);
      }
    }
    m = fmaxf(m, __shfl_xor(m, 16, 64));
    m = fmaxf(m, __shfl_xor(m, 32, 64));
    mx[qt] = m;

    float z = 0.f, e = 0.f;
#pragma unroll
    for (int tg = 0; tg < 8; ++tg) {
#pragma unroll
      for (int r = 0; r < 4; ++r) {
        float tt = accs[qt * 8 + tg][r] - m;
        float ex = exp2f(tt);  // native v_exp_f32 (base-2)
        z += ex;
        e = fmaf(ex, tt, e);   // ex==0 when masked: 0*finite, no NaN
        accs[qt * 8 + tg][r] = ex;
      }
    }
    z += __shfl_xor(z, 16, 64);
    z += __shfl_xor(z, 32, 64);
    e += __shfl_xor(e, 16, 64);
    e += __shfl_xor(e, 32, 64);
    if (cg == 0) { redM[qt][w][cl] = m; redZ[qt][w][cl] = z; redE[qt][w][cl] = e; }
  }
  __syncthreads();  // bar2: (m,z,e) triples ready — SINGLE softmax barrier

  // ---- online merge + normalize + bf16 att into LDS
#pragma unroll
  for (int qt = 0; qt < 2; ++qt) {
    const int l = lb * 32 + qt * 16 + cl;
    float M = redM[qt][0][cl];
#pragma unroll
    for (int i = 1; i < 8; ++i) M = fmaxf(M, redM[qt][i][cl]);
    float Z = 0.f, E = 0.f;
#pragma unroll
    for (int i = 0; i < 8; ++i) {
      float dm = redM[qt][i][cl] - M;          // <= 0, finite or 0
      float sci = exp2f(dm);
      Z += sci * redZ[qt][i][cl];
      E = fmaf(sci, fmaf(dm, redZ[qt][i][cl], redE[qt][i][cl]), E);
    }
    const float rz = __fdividef(1.0f, Z);
    if (w == 0 && cg == 0)
      out[OFF_ENT + ((size_t)b * HN + h) * LN + l] = LN2 * (__log2f(Z) - E * rz);

    const float scw = exp2f(mx[qt] - M) * rz;  // this wave's att scale
    unsigned char* arow = lds_att + (qt * 16 + cl) * APITCH;
#pragma unroll
    for (int tg = 0; tg < 8; ++tg) {
      const int s0 = w * 128 + tg * 16 + cg * 4;
      float ax = accs[qt * 8 + tg][0] * scw, ay = accs[qt * 8 + tg][1] * scw;
      float az = accs[qt * 8 + tg][2] * scw, aw = accs[qt * 8 + tg][3] * scw;
      uint2v pk = uint2v{rne2(ax, ay), rne2(az, aw)};
      *(uint2v*)(arow + s0 * 2) = pk;
    }
  }

  // ---- vT batch-0 prefetch (independent of LDS)
  const int et = w & 3, sh = w >> 2;
  const unsigned short* vbb =
      vT + ((size_t)(b * 8 + h) * 64 + et * 16 + cl) * 1024 + sh * 512;
  uint4v vf0[8];
#pragma unroll
  for (int j = 0; j < 8; ++j)
    vf0[j] = *(const uint4v*)(vbb + j * 32 + cg * 8);

  __syncthreads();  // bar3: full 32-row att tile visible

  // ---- PV FIRST: wave w -> (e-tile et, s-half sh); vT fragments reused
  // across both q-tiles. 32 MFMAs/wave.
  f32x4 acc00 = f32x4{0.f, 0.f, 0.f, 0.f}, acc01 = f32x4{0.f, 0.f, 0.f, 0.f};
  f32x4 acc10 = f32x4{0.f, 0.f, 0.f, 0.f}, acc11 = f32x4{0.f, 0.f, 0.f, 0.f};
#pragma unroll
  for (int scb = 0; scb < 2; ++scb) {
    uint4v vf[8];
    if (scb == 0) {
#pragma unroll
      for (int j = 0; j < 8; ++j) vf[j] = vf0[j];
    } else {
#pragma unroll
      for (int j = 0; j < 8; ++j)
        vf[j] = *(const uint4v*)(vbb + 256 + j * 32 + cg * 8);
    }
#pragma unroll
    for (int qt = 0; qt < 2; ++qt) {
      uint4v af[8];
#pragma unroll
      for (int j = 0; j < 8; ++j)
        af[j] = *(const uint4v*)(lds_att + (qt * 16 + cl) * APITCH +
                                 (sh * 512 + scb * 256 + j * 32 + cg * 8) * 2);
#pragma unroll
      for (int j = 0; j < 8; ++j) {
        bf16x8 a8 = __builtin_bit_cast(bf16x8, vf[j]);
        bf16x8 b8 = __builtin_bit_cast(bf16x8, af[j]);
        if (qt == 0) {
          if (j & 1)
            acc01 = __builtin_amdgcn_mfma_f32_16x16x32_bf16(a8, b8, acc01, 0, 0, 0);
          else
            acc00 = __builtin_amdgcn_mfma_f32_16x16x32_bf16(a8, b8, acc00, 0, 0, 0);
        } else {
          if (j & 1)
            acc11 = __builtin_amdgcn_mfma_f32_16x16x32_bf16(a8, b8, acc11, 0, 0, 0);
          else
            acc10 = __builtin_amdgcn_mfma_f32_16x16x32_bf16(a8, b8, acc10, 0, 0, 0);
        }
      }
    }
  }
  f32x4 sum0 = acc00 + acc01;
  f32x4 sum1 = acc10 + acc11;

  // ---- att NT store burst SECOND: wave w -> rows w*4..w*4+3
  {
    float* abase = out + OFF_ATT + (((size_t)b * HN + h) * LN + lb * 32) * SN;
#pragma unroll
    for (int rr = 0; rr < 4; ++rr) {
      const int row = w * 4 + rr;
      const unsigned char* src = lds_att + row * APITCH;
      float* dst = abase + (size_t)row * SN;
#pragma unroll
      for (int it = 0; it < 4; ++it) {
        uint2v pk = *(const uint2v*)(src + it * 512 + c * 8);
        f32x4 o = f32x4{__uint_as_float(pk.x << 16),
                        __uint_as_float(pk.x & 0xffff0000u),
                        __uint_as_float(pk.y << 16),
                        __uint_as_float(pk.y & 0xffff0000u)};
        __builtin_nontemporal_store(o, (f32x4*)(dst + it * 256 + c * 4));
      }
    }
  }

  __syncthreads();  // bar4: all PV att reads + att-write LDS reads done

  *(f32x4*)(lds_att + cl * APITCH + sh * 1024 + (et * 16 + cg * 4) * 4) = sum0;
  *(f32x4*)(lds_att + (16 + cl) * APITCH + sh * 1024 + (et * 16 + cg * 4) * 4) = sum1;

  __syncthreads();  // bar5: partials ready

  // ---- V: 2-way s-half reduce + coalesced NT store (512 thr = 32 r x 16 e4)
  {
    const int r = tid >> 4, e4 = tid & 15;
    f32x4 p0 = *(const f32x4*)(lds_att + r * APITCH + e4 * 16);
    f32x4 p1 = *(const f32x4*)(lds_att + r * APITCH + 1024 + e4 * 16);
    f32x4 s = p0 + p1;
    float* dst = out + (((size_t)b * LN + lb * 32 + r) * HN + h) * EN + e4 * 4;
    __builtin_nontemporal_store(s, (f32x4*)dst);
  }
}

extern "C" void kernel_launch(void* const* d_in, const int* in_sizes, int n_in,
                              void* d_out, int out_size, void* d_ws, size_t ws_size,
                              hipStream_t stream) {
  (void)in_sizes; (void)n_in; (void)out_size; (void)ws_size;
  const float* q   = (const float*)d_in[0];
  const float* k   = (const float*)d_in[1];
  const float* v   = (const float*)d_in[2];
  const float* phi = (const float*)d_in[4];
  const float* u   = (const float*)d_in[5];
  const float* lt  = (const float*)d_in[6];
  const float* th  = (const float*)d_in[7];
  const int*   cm  = (const int*)d_in[8];
  float* out = (float*)d_out;

  _Float16* mw = (_Float16*)((char*)d_ws + WS_MW);
  unsigned short* kb = (unsigned short*)((char*)d_ws + WS_KB);
  unsigned short* vT = (unsigned short*)((char*)d_ws + WS_VT);

  k_prep<<<dim3(10240), dim3(256), 0, stream>>>(k, v, phi, u, lt, th, mw, kb, vT);
  k_fused<<<dim3(128, 8, 1), dim3(512), 0, stream>>>(q, kb, vT, mw, cm, out);
}